// Round 8
// baseline (672.912 us; speedup 1.0000x reference)
//
#include <hip/hip_runtime.h>

typedef __attribute__((ext_vector_type(8))) _Float16 half8;
typedef __attribute__((ext_vector_type(4))) _Float16 half4;
typedef __attribute__((ext_vector_type(4))) float f32x4;

#define CDIM 256
#define NDIM 4096
#define MFMAH(a, b, c) __builtin_amdgcn_mfma_f32_16x16x32_f16((a), (b), (c), 0, 0, 0)

// async global->LDS DMA, 16B per lane (spill-proof staging path)
#define GLOAD_LDS16(gp, lp)                                              \
  __builtin_amdgcn_global_load_lds(                                      \
      (const __attribute__((address_space(1))) void*)(gp),               \
      (__attribute__((address_space(3))) void*)(lp), 16, 0, 0)

// ---------------------------------------------------------------------------
// Cast W matrices to fp16 once per launch (L2-resident afterwards).
// ---------------------------------------------------------------------------
__global__ void cast_w_kernel(const float* __restrict__ Wq,
                              const float* __restrict__ Wk,
                              const float* __restrict__ Wv,
                              _Float16* __restrict__ Wc) {
  int t = blockIdx.x * 256 + threadIdx.x;      // 49152 float4 groups total
  int mat = t >> 14;                            // /16384
  int idx = (t & 16383) * 4;
  const float* W = (mat == 0) ? Wq : (mat == 1 ? Wk : Wv);
  float4 w = *(const float4*)(W + idx);
  half4 h = {(_Float16)w.x, (_Float16)w.y, (_Float16)w.z, (_Float16)w.w};
  *(half4*)(Wc + mat * 65536 + idx) = h;
}

// ---------------------------------------------------------------------------
// Projection (round-6 version): Y = W X + b
// Q,K -> [b][n][c]; V -> [b][c][n].
// ---------------------------------------------------------------------------
__global__ __launch_bounds__(256, 2) void proj_kernel(
    const float* __restrict__ queries, const float* __restrict__ keys,
    const _Float16* __restrict__ Wc,
    const float* __restrict__ bq, const float* __restrict__ bk,
    const float* __restrict__ bv,
    _Float16* __restrict__ Qh, _Float16* __restrict__ Kh,
    _Float16* __restrict__ Vh)
{
  const int z = blockIdx.z, p = z >> 3, b = z & 7;
  const float* __restrict__ X = (p == 0) ? queries : keys;
  const _Float16* __restrict__ W = Wc + p * 65536;
  const float* __restrict__ bias = (p == 0) ? bq : (p == 1 ? bk : bv);
  const int n0 = blockIdx.x * 128;

  __shared__ __align__(16) _Float16 Xs[128][264];  // [n][c^swz], 528 B rows

  const int tid = threadIdx.x;
  const int wv = tid >> 6, lane = tid & 63, l16 = lane & 15, quad = lane >> 4;

#pragma unroll
  for (int it = 0; it < 8; ++it) {
    int id = tid + it * 256;
    int n4 = id & 31, c0 = (id >> 5) * 4;
    const float* Xp = &X[((size_t)(b * CDIM + c0)) * NDIM + n0 + n4 * 4];
    float4 x0 = *(const float4*)(Xp);
    float4 x1 = *(const float4*)(Xp + NDIM);
    float4 x2 = *(const float4*)(Xp + 2 * NDIM);
    float4 x3 = *(const float4*)(Xp + 3 * NDIM);
    const int cs = c0 ^ ((n4 & 7) << 3);
    half4 h;
    h = (half4){(_Float16)x0.x, (_Float16)x1.x, (_Float16)x2.x, (_Float16)x3.x};
    *(half4*)&Xs[n4 * 4 + 0][cs] = h;
    h = (half4){(_Float16)x0.y, (_Float16)x1.y, (_Float16)x2.y, (_Float16)x3.y};
    *(half4*)&Xs[n4 * 4 + 1][cs] = h;
    h = (half4){(_Float16)x0.z, (_Float16)x1.z, (_Float16)x2.z, (_Float16)x3.z};
    *(half4*)&Xs[n4 * 4 + 2][cs] = h;
    h = (half4){(_Float16)x0.w, (_Float16)x1.w, (_Float16)x2.w, (_Float16)x3.w};
    *(half4*)&Xs[n4 * 4 + 3][cs] = h;
  }
  __syncthreads();

  f32x4 acc[4][8];
#pragma unroll
  for (int og = 0; og < 4; ++og)
#pragma unroll
    for (int ng = 0; ng < 8; ++ng) acc[og][ng] = (f32x4){0.f, 0.f, 0.f, 0.f};

#pragma unroll
  for (int kc = 0; kc < 8; ++kc) {
    half8 wf[4], xf[8];
#pragma unroll
    for (int og = 0; og < 4; ++og)
      wf[og] = *(const half8*)(W + (wv * 64 + og * 16 + l16) * CDIM + kc * 32 + quad * 8);
#pragma unroll
    for (int ng = 0; ng < 8; ++ng) {
      const int row = ng * 16 + l16;
      xf[ng] = *(const half8*)&Xs[row][(kc * 32 + quad * 8) ^ (((row >> 2) & 7) << 3)];
    }
#pragma unroll
    for (int og = 0; og < 4; ++og)
#pragma unroll
      for (int ng = 0; ng < 8; ++ng)
        acc[og][ng] = MFMAH(wf[og], xf[ng], acc[og][ng]);
  }

#pragma unroll
  for (int og = 0; og < 4; ++og) {
    float4 b4 = *(const float4*)&bias[wv * 64 + og * 16 + quad * 4];
#pragma unroll
    for (int ng = 0; ng < 8; ++ng) {
      const int n = n0 + ng * 16 + l16;
      if (p == 2) {
#pragma unroll
        for (int r = 0; r < 4; ++r) {
          int o = wv * 64 + og * 16 + quad * 4 + r;
          float y = acc[og][ng][r] + ((const float*)&b4)[r];
          Vh[((size_t)(b * CDIM + o)) * NDIM + n] = (_Float16)y;
        }
      } else {
        half4 h4;
#pragma unroll
        for (int r = 0; r < 4; ++r)
          h4[r] = (_Float16)(acc[og][ng][r] + ((const float*)&b4)[r]);
        size_t idx = ((size_t)(b * NDIM + n)) * CDIM + wv * 64 + og * 16 + quad * 4;
        if (p == 0) *(half4*)&Qh[idx] = h4;
        else        *(half4*)&Kh[idx] = h4;
      }
    }
  }
}

// ---------------------------------------------------------------------------
// Flash attention, ONE barrier per jt + wave-private softmax/PV.
//  - PV computed as O^T = V P^T (D: m=c rows, n=i cols). Each wave owns its
//    16 i end-to-end: reads ONLY its own Ps rows (written by itself), so the
//    Ps-visibility barrier (B2) is gone; alpha/1-l are lane registers (Al/Li
//    deleted). V streamed from global (L2-resident; ~4x V L2 traffic, ok).
//  - Ks DOUBLE-buffered via global_load_lds DMA: DMA(jt+1) targets buf^1
//    right after the single loop-top barrier (buf^1 fully read last iter by
//    all waves; own-wave vmcnt drains at the next barrier). 2 -> 1 barrier.
//  - Between barriers everything is wave-private -> waves drift and fill
//    each other's stalls (the r6/r7 A/B showed TLP is the binding resource).
//  - QK layout, softmax (exp2), DMA source-swizzle: verbatim from round-6.
// ---------------------------------------------------------------------------
__global__ __launch_bounds__(256, 2) void attn_kernel(
    const float* __restrict__ queries, const float* __restrict__ mask,
    const _Float16* __restrict__ Qh, const _Float16* __restrict__ Kh,
    const _Float16* __restrict__ Vh, float* __restrict__ out)
{
  extern __shared__ __align__(16) char smem[];
  _Float16* const KsB = (_Float16*)smem;           // 2 bufs x 16384 halfs
  _Float16* const Ps  = (_Float16*)(smem + 65536); // 64 x 72 halfs

  const int blk = blockIdx.x, b = blk & 7, it = blk >> 3;  // b=blk&7: XCD L2
  const int i0 = it * 64;

  const int tid = threadIdx.x;
  const int wv = tid >> 6, lane = tid & 63, l16 = lane & 15, quad = lane >> 4;

  const float LOG2E = 1.44269504088896f;

  // Q fragments: B-operand layout (n=l16 -> i-row, k=quad*8+t -> c)
  half8 qf[8];
  {
    const size_t qrow = ((size_t)(b * NDIM + i0 + wv * 16 + l16)) * CDIM;
#pragma unroll
    for (int kc = 0; kc < 8; ++kc)
      qf[kc] = *(const half8*)(Qh + qrow + kc * 32 + quad * 8);
  }
  const float mv = mask[(size_t)b * NDIM + i0 + wv * 16 + l16];
  const float mvalL = mv * LOG2E;
  float m_run = -1e30f, l_run = 0.f;

  // O^T: lane holds c = cg*16 + quad*4 + r, i = i0 + wv*16 + l16 (fixed)
  f32x4 O[16];
#pragma unroll
  for (int cg = 0; cg < 16; ++cg) O[cg] = (f32x4){0.f, 0.f, 0.f, 0.f};

  const _Float16* __restrict__ Kb = Kh + (size_t)b * NDIM * CDIM;
  const _Float16* __restrict__ Vb = Vh + (size_t)b * CDIM * NDIM;

  // staging geometry (round-6 proven): source col pre-swizzled so linear LDS
  // + swizzled ds_read is conflict-spread.
  const int jrow = tid >> 5;                                   // 0..7
  const int scol = ((tid & 31) * 8) ^ ((jrow & 7) << 3);       // halfs
  const int kswz = (l16 & 7) << 3;                             // read-side XOR

  // prologue: DMA K tile 0 -> buf 0
#pragma unroll
  for (int st = 0; st < 8; ++st)
    GLOAD_LDS16(Kb + (size_t)(st * 8 + jrow) * CDIM + scol,
                smem + tid * 16 + st * 4096);

  for (int jt = 0; jt < 64; ++jt) {
    const int j0 = jt * 64;
    const int pb = jt & 1;
    __syncthreads();  // the ONLY barrier: DMA(jt) drained (own vmcnt) by all
                      // waves; buf[pb^1] fully read by all waves last iter.

    // issue DMA(jt+1) into buf^1 now -> whole body hides the latency
    if (jt < 63) {
      const _Float16* srcn = Kb + (size_t)((jt + 1) * 64 + jrow) * CDIM + scol;
      char* dstn = smem + (pb ^ 1) * 32768 + tid * 16;
#pragma unroll
      for (int st = 0; st < 8; ++st)
        GLOAD_LDS16(srcn + (size_t)st * 8 * CDIM, dstn + st * 4096);
    }

    const _Float16* KsP = KsB + pb * 16384;

    // S^T = K Q^T: D[m=j][n=i]; lane holds 16 j for i = i0+wv*16+l16
    f32x4 s[4];
#pragma unroll
    for (int js = 0; js < 4; ++js) s[js] = (f32x4){0.f, 0.f, 0.f, 0.f};
#pragma unroll
    for (int kc = 0; kc < 8; ++kc) {
#pragma unroll
      for (int js = 0; js < 4; ++js) {
        half8 kf = *(const half8*)&KsP[(js * 16 + l16) * 256 +
                                       ((kc * 32 + quad * 8) ^ kswz)];
        s[js] = MFMAH(kf, qf[kc], s[js]);
      }
    }

    // online softmax (exp2 domain) — wave-private
    float a[16];
    float mx = -1e30f;
#pragma unroll
    for (int js = 0; js < 4; ++js)
#pragma unroll
      for (int r = 0; r < 4; ++r) {
        float v = s[js][r] * mvalL;
        a[js * 4 + r] = v;
        mx = fmaxf(mx, v);
      }
    mx = fmaxf(mx, __shfl_xor(mx, 16));
    mx = fmaxf(mx, __shfl_xor(mx, 32));
    const float mnew = fmaxf(m_run, mx);
    const float alpha = exp2f(m_run - mnew);
    m_run = mnew;
    float psum = 0.f;
#pragma unroll
    for (int js = 0; js < 4; ++js) {
      float p0 = exp2f(a[js * 4 + 0] - mnew);
      float p1 = exp2f(a[js * 4 + 1] - mnew);
      float p2 = exp2f(a[js * 4 + 2] - mnew);
      float p3 = exp2f(a[js * 4 + 3] - mnew);
      psum += (p0 + p1) + (p2 + p3);
      half4 hp = {(_Float16)p0, (_Float16)p1, (_Float16)p2, (_Float16)p3};
      // P[i][j]: i = wv*16+l16 (OWN row), j = js*16 + quad*4 + r
      *(half4*)&Ps[(wv * 16 + l16) * 72 + js * 16 + quad * 4] = hp;
    }
    psum += __shfl_xor(psum, 16);
    psum += __shfl_xor(psum, 32);
    l_run = l_run * alpha + psum;

    // PV (wave-private): O^T += V P^T. alpha is lane-uniform -> scalar mul.
#pragma unroll
    for (int cg = 0; cg < 16; ++cg)
#pragma unroll
      for (int r = 0; r < 4; ++r) O[cg][r] *= alpha;
    // P^T B-frags from OWN Ps row (lgkmcnt auto-inserted; no barrier needed)
    half8 pf0 = *(const half8*)&Ps[(wv * 16 + l16) * 72 + quad * 8];
    half8 pf1 = *(const half8*)&Ps[(wv * 16 + l16) * 72 + 32 + quad * 8];
    const _Float16* vrow = Vb + (size_t)l16 * NDIM + j0 + quad * 8;
#pragma unroll
    for (int cg = 0; cg < 16; ++cg) {
      half8 va0 = *(const half8*)(vrow);
      half8 va1 = *(const half8*)(vrow + 32);
      O[cg] = MFMAH(va0, pf0, O[cg]);
      O[cg] = MFMAH(va1, pf1, O[cg]);
      vrow += (size_t)16 * NDIM;
    }
  }

  // epilogue: lane-uniform 1/l; c = cg*16+quad*4+r, i = i0+wv*16+l16
  const float sc = (1.f - mv) / l_run;
#pragma unroll
  for (int cg = 0; cg < 16; ++cg) {
#pragma unroll
    for (int r = 0; r < 4; ++r) {
      const int c = cg * 16 + quad * 4 + r;
      const size_t base = ((size_t)(b * CDIM + c)) * NDIM + i0 + wv * 16 + l16;
      out[base] = queries[base] * mv + sc * O[cg][r];
    }
  }
}

extern "C" void kernel_launch(void* const* d_in, const int* in_sizes, int n_in,
                              void* d_out, int out_size, void* d_ws, size_t ws_size,
                              hipStream_t stream) {
  const float* queries = (const float*)d_in[0];
  const float* keys    = (const float*)d_in[1];
  const float* mask    = (const float*)d_in[2];
  const float* Wq = (const float*)d_in[3];
  const float* bq = (const float*)d_in[4];
  const float* Wk = (const float*)d_in[5];
  const float* bk = (const float*)d_in[6];
  const float* Wv = (const float*)d_in[7];
  const float* bv = (const float*)d_in[8];
  float* out = (float*)d_out;

  const size_t elems = (size_t)8 * NDIM * CDIM;
  _Float16* Qh = (_Float16*)d_ws;
  _Float16* Kh = Qh + elems;
  _Float16* Vh = Kh + elems;
  _Float16* Wc = Vh + elems;   // 3*65536 fp16

  cast_w_kernel<<<dim3(192), 256, 0, stream>>>(Wq, Wk, Wv, Wc);
  proj_kernel<<<dim3(32, 1, 24), 256, 0, stream>>>(
      queries, keys, Wc, bq, bk, bv, Qh, Kh, Vh);
  // dynamic LDS: Ks dbuf 65536 B + Ps 9216 B = 74752 B
  attn_kernel<<<dim3(512), 256, 74752, stream>>>(
      queries, mask, Qh, Kh, Vh, out);
}

// Round 9
// 397.715 us; speedup vs baseline: 1.6919x; 1.6919x over previous
//
#include <hip/hip_runtime.h>

typedef __attribute__((ext_vector_type(8))) _Float16 half8;
typedef __attribute__((ext_vector_type(4))) _Float16 half4;
typedef __attribute__((ext_vector_type(4))) float f32x4;

#define CDIM 256
#define NDIM 4096
#define MFMAH(a, b, c) __builtin_amdgcn_mfma_f32_16x16x32_f16((a), (b), (c), 0, 0, 0)

// async global->LDS DMA, 16B per lane (spill-proof staging path)
#define GLOAD_LDS16(gp, lp)                                              \
  __builtin_amdgcn_global_load_lds(                                      \
      (const __attribute__((address_space(1))) void*)(gp),               \
      (__attribute__((address_space(3))) void*)(lp), 16, 0, 0)

// ---------------------------------------------------------------------------
// Cast W matrices to fp16 once per launch (L2-resident afterwards).
// ---------------------------------------------------------------------------
__global__ void cast_w_kernel(const float* __restrict__ Wq,
                              const float* __restrict__ Wk,
                              const float* __restrict__ Wv,
                              _Float16* __restrict__ Wc) {
  int t = blockIdx.x * 256 + threadIdx.x;      // 49152 float4 groups total
  int mat = t >> 14;                            // /16384
  int idx = (t & 16383) * 4;
  const float* W = (mat == 0) ? Wq : (mat == 1 ? Wk : Wv);
  float4 w = *(const float4*)(W + idx);
  half4 h = {(_Float16)w.x, (_Float16)w.y, (_Float16)w.z, (_Float16)w.w};
  *(half4*)(Wc + mat * 65536 + idx) = h;
}

// ---------------------------------------------------------------------------
// Projection, K/V-FUSED: proj is HBM-bound (~594 MB at ~6 TB/s); the keys
// tensor was read TWICE (K pass + V pass) = 134 MB avoidable. Here z<8 ->
// Q-block (1 GEMM from queries); z>=8 -> KV-block: stage keys tile ONCE,
// run Wk-GEMM (-> Kh [b][n][c]) then Wv-GEMM (-> Vh [b][c][n]) sequentially
// against the same LDS tile (acc reused; W frags from L2). Dispatch order:
// blocks 0-255 = all Q, 256-511 = all KV -> each CU gets 1 Q + 1 KV
// (balanced ~3T makespan). GEMM core unchanged from the proven version.
// ---------------------------------------------------------------------------
__global__ __launch_bounds__(256, 2) void proj_kernel(
    const float* __restrict__ queries, const float* __restrict__ keys,
    const _Float16* __restrict__ Wc,
    const float* __restrict__ bq, const float* __restrict__ bk,
    const float* __restrict__ bv,
    _Float16* __restrict__ Qh, _Float16* __restrict__ Kh,
    _Float16* __restrict__ Vh)
{
  const int z = blockIdx.z, p2 = z >> 3, b = z & 7;   // p2: 0=Q, 1=K+V
  const float* __restrict__ X = (p2 == 0) ? queries : keys;
  const int n0 = blockIdx.x * 128;

  __shared__ __align__(16) _Float16 Xs[128][264];  // [n][c^swz], 528 B rows

  const int tid = threadIdx.x;
  const int wv = tid >> 6, lane = tid & 63, l16 = lane & 15, quad = lane >> 4;

#pragma unroll
  for (int it = 0; it < 8; ++it) {
    int id = tid + it * 256;
    int n4 = id & 31, c0 = (id >> 5) * 4;
    const float* Xp = &X[((size_t)(b * CDIM + c0)) * NDIM + n0 + n4 * 4];
    float4 x0 = *(const float4*)(Xp);
    float4 x1 = *(const float4*)(Xp + NDIM);
    float4 x2 = *(const float4*)(Xp + 2 * NDIM);
    float4 x3 = *(const float4*)(Xp + 3 * NDIM);
    const int cs = c0 ^ ((n4 & 7) << 3);
    half4 h;
    h = (half4){(_Float16)x0.x, (_Float16)x1.x, (_Float16)x2.x, (_Float16)x3.x};
    *(half4*)&Xs[n4 * 4 + 0][cs] = h;
    h = (half4){(_Float16)x0.y, (_Float16)x1.y, (_Float16)x2.y, (_Float16)x3.y};
    *(half4*)&Xs[n4 * 4 + 1][cs] = h;
    h = (half4){(_Float16)x0.z, (_Float16)x1.z, (_Float16)x2.z, (_Float16)x3.z};
    *(half4*)&Xs[n4 * 4 + 2][cs] = h;
    h = (half4){(_Float16)x0.w, (_Float16)x1.w, (_Float16)x2.w, (_Float16)x3.w};
    *(half4*)&Xs[n4 * 4 + 3][cs] = h;
  }
  __syncthreads();

  const int npass = 1 + p2;  // Q: 1 pass; KV: 2 passes
  for (int ps = 0; ps < npass; ++ps) {
    const int pe = p2 + ps;  // 0=Q, 1=K, 2=V
    const _Float16* __restrict__ W = Wc + pe * 65536;
    const float* __restrict__ bias = (pe == 0) ? bq : (pe == 1 ? bk : bv);

    f32x4 acc[4][8];
#pragma unroll
    for (int og = 0; og < 4; ++og)
#pragma unroll
      for (int ng = 0; ng < 8; ++ng) acc[og][ng] = (f32x4){0.f, 0.f, 0.f, 0.f};

#pragma unroll
    for (int kc = 0; kc < 8; ++kc) {
      half8 wf[4], xf[8];
#pragma unroll
      for (int og = 0; og < 4; ++og)
        wf[og] = *(const half8*)(W + (wv * 64 + og * 16 + l16) * CDIM + kc * 32 + quad * 8);
#pragma unroll
      for (int ng = 0; ng < 8; ++ng) {
        const int row = ng * 16 + l16;
        xf[ng] = *(const half8*)&Xs[row][(kc * 32 + quad * 8) ^ (((row >> 2) & 7) << 3)];
      }
#pragma unroll
      for (int og = 0; og < 4; ++og)
#pragma unroll
        for (int ng = 0; ng < 8; ++ng)
          acc[og][ng] = MFMAH(wf[og], xf[ng], acc[og][ng]);
    }

#pragma unroll
    for (int og = 0; og < 4; ++og) {
      float4 b4 = *(const float4*)&bias[wv * 64 + og * 16 + quad * 4];
#pragma unroll
      for (int ng = 0; ng < 8; ++ng) {
        const int n = n0 + ng * 16 + l16;
        if (pe == 2) {
#pragma unroll
          for (int r = 0; r < 4; ++r) {
            int o = wv * 64 + og * 16 + quad * 4 + r;
            float y = acc[og][ng][r] + ((const float*)&b4)[r];
            Vh[((size_t)(b * CDIM + o)) * NDIM + n] = (_Float16)y;
          }
        } else {
          half4 h4;
#pragma unroll
          for (int r = 0; r < 4; ++r)
            h4[r] = (_Float16)(acc[og][ng][r] + ((const float*)&b4)[r]);
          size_t idx = ((size_t)(b * NDIM + n)) * CDIM + wv * 64 + og * 16 + quad * 4;
          if (pe == 0) *(half4*)&Qh[idx] = h4;
          else         *(half4*)&Kh[idx] = h4;
        }
      }
    }
  }
}

// ---------------------------------------------------------------------------
// Flash attention: round-6 kernel VERBATIM (twice-proven 220 us).
//  1. K staging via global_load_lds DMA, linear LDS + source-content swizzle.
//  2. DMA(jt+1) issued after B2 -> PV phase covers the latency.
//  3. exp2-domain softmax (mask premultiplied by log2e).
// ---------------------------------------------------------------------------
__global__ __launch_bounds__(256, 2) void attn_kernel(
    const float* __restrict__ queries, const float* __restrict__ mask,
    const _Float16* __restrict__ Qh, const _Float16* __restrict__ Kh,
    const _Float16* __restrict__ Vh, float* __restrict__ out)
{
  const int blk = blockIdx.x, b = blk & 7, it = blk >> 3;  // b=blk&7: XCD L2
  const int i0 = it * 64;

  __shared__ __align__(16) _Float16 Ks[64 * 256];   // linear, swizzled content
  __shared__ __align__(16) _Float16 Ps[2][64][72];  // [i][j]  18432 B (dbuf)
  __shared__ __align__(16) float Al[2][64];         // alpha per i-row (dbuf)
  __shared__ __align__(16) float Li[64];            // 1/l per i-row

  const int tid = threadIdx.x;
  const int wv = tid >> 6, lane = tid & 63, l16 = lane & 15, quad = lane >> 4;

  const float LOG2E = 1.44269504088896f;

  // Q fragments: B-operand layout (n=l16 -> i-row, k=quad*8+t -> c)
  half8 qf[8];
  {
    const size_t qrow = ((size_t)(b * NDIM + i0 + wv * 16 + l16)) * CDIM;
#pragma unroll
    for (int kc = 0; kc < 8; ++kc)
      qf[kc] = *(const half8*)(Qh + qrow + kc * 32 + quad * 8);
  }
  // per-lane softmax state: this lane's i-row is i0 + wv*16 + l16
  const float mvalL = mask[(size_t)b * NDIM + i0 + wv * 16 + l16] * LOG2E;
  float m_run = -1e30f, l_run = 0.f;

  f32x4 O[4][4];  // [i-group][ch-group], wave's ch base = wv*64
#pragma unroll
  for (int g = 0; g < 4; ++g)
#pragma unroll
    for (int cg = 0; cg < 4; ++cg) O[g][cg] = (f32x4){0.f, 0.f, 0.f, 0.f};

  const _Float16* __restrict__ Kb = Kh + (size_t)b * NDIM * CDIM;
  const _Float16* __restrict__ Vw = Vh + ((size_t)(b * CDIM + wv * 64)) * NDIM;

  // staging geometry (loop-invariant): thread handles chunk row jrow (0..7),
  // 16B block (tid&31) of each 512B K row; source col pre-swizzled.
  const int jrow = tid >> 5;                                   // 0..7
  const int scol = ((tid & 31) * 8) ^ ((jrow & 7) << 3);       // halfs
  char* const ldst0 = (char*)Ks + (size_t)tid * 16;            // +st*4096
  const int kswz = (l16 & 7) << 3;                             // read-side XOR

  // prologue: issue DMA for K tile 0
#pragma unroll
  for (int st = 0; st < 8; ++st)
    GLOAD_LDS16(Kb + (size_t)(st * 8 + jrow) * CDIM + scol, ldst0 + st * 4096);

  for (int jt = 0; jt < 64; ++jt) {
    const int j0 = jt * 64;
    const int pb = jt & 1;
    // V fragments for this tile direct from global (held across QK/softmax)
    half8 vf[2][4];
#pragma unroll
    for (int kk = 0; kk < 2; ++kk)
#pragma unroll
      for (int cg = 0; cg < 4; ++cg)
        vf[kk][cg] = *(const half8*)(Vw + (size_t)(cg * 16 + l16) * NDIM + j0 + kk * 32 + quad * 8);
    __syncthreads();  // B1: barrier drain (vmcnt 0) completes K DMA

    // S^T = K Q^T: D[m=j][n=i]; lane holds 16 j-values for i = wv*16+l16
    f32x4 s[4];
#pragma unroll
    for (int js = 0; js < 4; ++js) s[js] = (f32x4){0.f, 0.f, 0.f, 0.f};
#pragma unroll
    for (int kc = 0; kc < 8; ++kc) {
#pragma unroll
      for (int js = 0; js < 4; ++js) {
        half8 kf = *(const half8*)&Ks[(js * 16 + l16) * 256 + ((kc * 32 + quad * 8) ^ kswz)];
        s[js] = MFMAH(kf, qf[kc], s[js]);
      }
    }

    // online softmax (exp2 domain), in-lane over 16 j + cross-quad reduce
    float a[16];
    float mx = -1e30f;
#pragma unroll
    for (int js = 0; js < 4; ++js)
#pragma unroll
      for (int r = 0; r < 4; ++r) {
        float v = s[js][r] * mvalL;
        a[js * 4 + r] = v;
        mx = fmaxf(mx, v);
      }
    mx = fmaxf(mx, __shfl_xor(mx, 16));
    mx = fmaxf(mx, __shfl_xor(mx, 32));
    const float mnew = fmaxf(m_run, mx);
    const float alpha = exp2f(m_run - mnew);
    m_run = mnew;
    float psum = 0.f;
#pragma unroll
    for (int js = 0; js < 4; ++js) {
      float p0 = exp2f(a[js * 4 + 0] - mnew);
      float p1 = exp2f(a[js * 4 + 1] - mnew);
      float p2 = exp2f(a[js * 4 + 2] - mnew);
      float p3 = exp2f(a[js * 4 + 3] - mnew);
      psum += (p0 + p1) + (p2 + p3);
      half4 hp = {(_Float16)p0, (_Float16)p1, (_Float16)p2, (_Float16)p3};
      // P[i][j]: i = wv*16+l16, j = js*16 + quad*4 + r
      *(half4*)&Ps[pb][wv * 16 + l16][js * 16 + quad * 4] = hp;
    }
    psum += __shfl_xor(psum, 16);
    psum += __shfl_xor(psum, 32);
    l_run = l_run * alpha + psum;
    if (quad == 0) Al[pb][wv * 16 + l16] = alpha;
    __syncthreads();  // B2: Ps/Al visible; all Ks reads of jt complete

    // issue NEXT K tile's DMA now -> latency hidden under PV + next loop-top
    if (jt < 63) {
      const _Float16* srcn = Kb + (size_t)((jt + 1) * 64 + jrow) * CDIM + scol;
#pragma unroll
      for (int st = 0; st < 8; ++st)
        GLOAD_LDS16(srcn + (size_t)st * 8 * CDIM, ldst0 + st * 4096);
    }

    // O rescale + O += P V  (wave covers all 64 i, channels [wv*64, +64))
    f32x4 av[4];
#pragma unroll
    for (int g = 0; g < 4; ++g) av[g] = *(const f32x4*)&Al[pb][g * 16 + quad * 4];
#pragma unroll
    for (int g = 0; g < 4; ++g)
#pragma unroll
      for (int cg = 0; cg < 4; ++cg)
#pragma unroll
        for (int r = 0; r < 4; ++r) O[g][cg][r] *= av[g][r];
#pragma unroll
    for (int kk = 0; kk < 2; ++kk) {
      half8 pa[4];
#pragma unroll
      for (int g = 0; g < 4; ++g)
        pa[g] = *(const half8*)&Ps[pb][g * 16 + l16][kk * 32 + quad * 8];
#pragma unroll
      for (int g = 0; g < 4; ++g)
#pragma unroll
        for (int cg = 0; cg < 4; ++cg)
          O[g][cg] = MFMAH(pa[g], vf[kk][cg], O[g][cg]);
    }
  }

  // publish 1/l, then blended epilogue
  if (quad == 0) Li[wv * 16 + l16] = 1.0f / l_run;
  __syncthreads();
#pragma unroll
  for (int g = 0; g < 4; ++g) {
    f32x4 li4 = *(const f32x4*)&Li[g * 16 + quad * 4];
    const int i = i0 + g * 16 + quad * 4;
    float4 m4 = *(const float4*)&mask[(size_t)b * NDIM + i];
#pragma unroll
    for (int cg = 0; cg < 4; ++cg) {
      const int c = wv * 64 + cg * 16 + l16;
      const size_t base = ((size_t)(b * CDIM + c)) * NDIM + i;
      float4 q4 = *(const float4*)(queries + base);
      float4 o4;
      o4.x = q4.x * m4.x + (1.f - m4.x) * (O[g][cg][0] * li4[0]);
      o4.y = q4.y * m4.y + (1.f - m4.y) * (O[g][cg][1] * li4[1]);
      o4.z = q4.z * m4.z + (1.f - m4.z) * (O[g][cg][2] * li4[2]);
      o4.w = q4.w * m4.w + (1.f - m4.w) * (O[g][cg][3] * li4[3]);
      *(float4*)(out + base) = o4;
    }
  }
}

extern "C" void kernel_launch(void* const* d_in, const int* in_sizes, int n_in,
                              void* d_out, int out_size, void* d_ws, size_t ws_size,
                              hipStream_t stream) {
  const float* queries = (const float*)d_in[0];
  const float* keys    = (const float*)d_in[1];
  const float* mask    = (const float*)d_in[2];
  const float* Wq = (const float*)d_in[3];
  const float* bq = (const float*)d_in[4];
  const float* Wk = (const float*)d_in[5];
  const float* bk = (const float*)d_in[6];
  const float* Wv = (const float*)d_in[7];
  const float* bv = (const float*)d_in[8];
  float* out = (float*)d_out;

  const size_t elems = (size_t)8 * NDIM * CDIM;
  _Float16* Qh = (_Float16*)d_ws;
  _Float16* Kh = Qh + elems;
  _Float16* Vh = Kh + elems;
  _Float16* Wc = Vh + elems;   // 3*65536 fp16

  cast_w_kernel<<<dim3(192), 256, 0, stream>>>(Wq, Wk, Wv, Wc);
  proj_kernel<<<dim3(32, 1, 16), 256, 0, stream>>>(
      queries, keys, Wc, bq, bk, bv, Qh, Kh, Vh);
  attn_kernel<<<dim3(512), 256, 0, stream>>>(
      queries, mask, Qh, Kh, Vh, out);
}

// Round 10
// 327.523 us; speedup vs baseline: 2.0546x; 1.2143x over previous
//
#include <hip/hip_runtime.h>

typedef __attribute__((ext_vector_type(8))) _Float16 half8;
typedef __attribute__((ext_vector_type(4))) _Float16 half4;
typedef __attribute__((ext_vector_type(4))) float f32x4;

#define CDIM 256
#define NDIM 4096
#define MFMAH(a, b, c) __builtin_amdgcn_mfma_f32_16x16x32_f16((a), (b), (c), 0, 0, 0)

// async global->LDS DMA, 16B per lane (spill-proof staging path)
#define GLOAD_LDS16(gp, lp)                                              \
  __builtin_amdgcn_global_load_lds(                                      \
      (const __attribute__((address_space(1))) void*)(gp),               \
      (__attribute__((address_space(3))) void*)(lp), 16, 0, 0)

// ---------------------------------------------------------------------------
// Cast W matrices to fp16 once per launch (L2-resident afterwards).
// ---------------------------------------------------------------------------
__global__ void cast_w_kernel(const float* __restrict__ Wq,
                              const float* __restrict__ Wk,
                              const float* __restrict__ Wv,
                              _Float16* __restrict__ Wc) {
  int t = blockIdx.x * 256 + threadIdx.x;      // 49152 float4 groups total
  int mat = t >> 14;                            // /16384
  int idx = (t & 16383) * 4;
  const float* W = (mat == 0) ? Wq : (mat == 1 ? Wk : Wv);
  float4 w = *(const float4*)(W + idx);
  half4 h = {(_Float16)w.x, (_Float16)w.y, (_Float16)w.z, (_Float16)w.w};
  *(half4*)(Wc + mat * 65536 + idx) = h;
}

// ---------------------------------------------------------------------------
// Projection (round-0 original, best-proven): Y[b,o,n] = sum_c W[o,c] X[b,c,n]
// + b[o]. n-tile 128, full o (256). Q,K -> [b][n][c]; V -> [b][c][n].
// (KV-fusion reverted: r9 showed the doubled KV-block critical path costs
//  ~60 us in makespan — more than the 134 MB HBM saving buys.)
// ---------------------------------------------------------------------------
__global__ __launch_bounds__(256, 2) void proj_kernel(
    const float* __restrict__ queries, const float* __restrict__ keys,
    const _Float16* __restrict__ Wc,
    const float* __restrict__ bq, const float* __restrict__ bk,
    const float* __restrict__ bv,
    _Float16* __restrict__ Qh, _Float16* __restrict__ Kh,
    _Float16* __restrict__ Vh)
{
  const int z = blockIdx.z, p = z >> 3, b = z & 7;
  const float* __restrict__ X = (p == 0) ? queries : keys;
  const _Float16* __restrict__ W = Wc + p * 65536;
  const float* __restrict__ bias = (p == 0) ? bq : (p == 1 ? bk : bv);
  const int n0 = blockIdx.x * 128;

  __shared__ __align__(16) _Float16 Xs[128][264];  // [n][c], 528 B rows

  const int tid = threadIdx.x;
  const int wv = tid >> 6, lane = tid & 63, l16 = lane & 15, quad = lane >> 4;

  // stage X tile 128n x 256c (transpose c-major global -> Xs[n][c])
#pragma unroll
  for (int it = 0; it < 32; ++it) {
    int id = tid + it * 256;
    int c = id >> 5, n4 = id & 31;
    float4 x = *(const float4*)&X[((size_t)(b * CDIM + c)) * NDIM + n0 + n4 * 4];
    Xs[n4 * 4 + 0][c] = (_Float16)x.x;
    Xs[n4 * 4 + 1][c] = (_Float16)x.y;
    Xs[n4 * 4 + 2][c] = (_Float16)x.z;
    Xs[n4 * 4 + 3][c] = (_Float16)x.w;
  }
  __syncthreads();

  f32x4 acc[4][8];
#pragma unroll
  for (int og = 0; og < 4; ++og)
#pragma unroll
    for (int ng = 0; ng < 8; ++ng) acc[og][ng] = (f32x4){0.f, 0.f, 0.f, 0.f};

#pragma unroll
  for (int kc = 0; kc < 8; ++kc) {
    half8 wf[4], xf[8];
#pragma unroll
    for (int og = 0; og < 4; ++og)
      wf[og] = *(const half8*)(W + (wv * 64 + og * 16 + l16) * CDIM + kc * 32 + quad * 8);
#pragma unroll
    for (int ng = 0; ng < 8; ++ng)
      xf[ng] = *(const half8*)&Xs[ng * 16 + l16][kc * 32 + quad * 8];
#pragma unroll
    for (int og = 0; og < 4; ++og)
#pragma unroll
      for (int ng = 0; ng < 8; ++ng)
        acc[og][ng] = MFMAH(wf[og], xf[ng], acc[og][ng]);
  }

  // epilogue: D rows = o (quad*4+r), cols = n (l16)
#pragma unroll
  for (int og = 0; og < 4; ++og) {
    float4 b4 = *(const float4*)&bias[wv * 64 + og * 16 + quad * 4];
#pragma unroll
    for (int ng = 0; ng < 8; ++ng) {
      const int n = n0 + ng * 16 + l16;
      if (p == 2) {
#pragma unroll
        for (int r = 0; r < 4; ++r) {
          int o = wv * 64 + og * 16 + quad * 4 + r;
          float y = acc[og][ng][r] + ((const float*)&b4)[r];
          Vh[((size_t)(b * CDIM + o)) * NDIM + n] = (_Float16)y;
        }
      } else {
        half4 h4;
#pragma unroll
        for (int r = 0; r < 4; ++r)
          h4[r] = (_Float16)(acc[og][ng][r] + ((const float*)&b4)[r]);
        size_t idx = ((size_t)(b * NDIM + n)) * CDIM + wv * 64 + og * 16 + quad * 4;
        if (p == 0) *(half4*)&Qh[idx] = h4;
        else        *(half4*)&Kh[idx] = h4;
      }
    }
  }
}

// ---------------------------------------------------------------------------
// Flash attention: round-6 kernel with ONE change — Ps rows padded 72 -> 88
// halfs (176 B, 16B-aligned).
// Theory: the 2.307e7 bank conflicts (identical across r0/r6/r9, dropped 11x
// only when r3 changed Ps) come from Ps: 144B rows => stride/4 == 4 (mod 32)
// => pa-read start bank = 4*(l16+quad) mod 32 => 8 lanes/bank-group = 8-way
// conflict; predicted 745 cy/block/jt matches measured 704. 176B rows =>
// stride/4 == 12 (mod 32) => 4-way max on reads, ~2-way writes.
// Everything else verbatim: DMA K staging + source swizzle, post-B2 DMA
// prefetch, exp2 softmax, Al/Li rescale, blended epilogue.
// ---------------------------------------------------------------------------
__global__ __launch_bounds__(256, 2) void attn_kernel(
    const float* __restrict__ queries, const float* __restrict__ mask,
    const _Float16* __restrict__ Qh, const _Float16* __restrict__ Kh,
    const _Float16* __restrict__ Vh, float* __restrict__ out)
{
  const int blk = blockIdx.x, b = blk & 7, it = blk >> 3;  // b=blk&7: XCD L2
  const int i0 = it * 64;

  __shared__ __align__(16) _Float16 Ks[64 * 256];   // linear, swizzled content
  __shared__ __align__(16) _Float16 Ps[2][64][88];  // [i][j] 176B rows (pad)
  __shared__ __align__(16) float Al[2][64];         // alpha per i-row (dbuf)
  __shared__ __align__(16) float Li[64];            // 1/l per i-row

  const int tid = threadIdx.x;
  const int wv = tid >> 6, lane = tid & 63, l16 = lane & 15, quad = lane >> 4;

  const float LOG2E = 1.44269504088896f;

  // Q fragments: B-operand layout (n=l16 -> i-row, k=quad*8+t -> c)
  half8 qf[8];
  {
    const size_t qrow = ((size_t)(b * NDIM + i0 + wv * 16 + l16)) * CDIM;
#pragma unroll
    for (int kc = 0; kc < 8; ++kc)
      qf[kc] = *(const half8*)(Qh + qrow + kc * 32 + quad * 8);
  }
  // per-lane softmax state: this lane's i-row is i0 + wv*16 + l16
  const float mvalL = mask[(size_t)b * NDIM + i0 + wv * 16 + l16] * LOG2E;
  float m_run = -1e30f, l_run = 0.f;

  f32x4 O[4][4];  // [i-group][ch-group], wave's ch base = wv*64
#pragma unroll
  for (int g = 0; g < 4; ++g)
#pragma unroll
    for (int cg = 0; cg < 4; ++cg) O[g][cg] = (f32x4){0.f, 0.f, 0.f, 0.f};

  const _Float16* __restrict__ Kb = Kh + (size_t)b * NDIM * CDIM;
  const _Float16* __restrict__ Vw = Vh + ((size_t)(b * CDIM + wv * 64)) * NDIM;

  // staging geometry (loop-invariant): thread handles chunk row jrow (0..7),
  // 16B block (tid&31) of each 512B K row; source col pre-swizzled.
  const int jrow = tid >> 5;                                   // 0..7
  const int scol = ((tid & 31) * 8) ^ ((jrow & 7) << 3);       // halfs
  char* const ldst0 = (char*)Ks + (size_t)tid * 16;            // +st*4096
  const int kswz = (l16 & 7) << 3;                             // read-side XOR

  // prologue: issue DMA for K tile 0
#pragma unroll
  for (int st = 0; st < 8; ++st)
    GLOAD_LDS16(Kb + (size_t)(st * 8 + jrow) * CDIM + scol, ldst0 + st * 4096);

  for (int jt = 0; jt < 64; ++jt) {
    const int j0 = jt * 64;
    const int pb = jt & 1;
    // V fragments for this tile direct from global (held across QK/softmax)
    half8 vf[2][4];
#pragma unroll
    for (int kk = 0; kk < 2; ++kk)
#pragma unroll
      for (int cg = 0; cg < 4; ++cg)
        vf[kk][cg] = *(const half8*)(Vw + (size_t)(cg * 16 + l16) * NDIM + j0 + kk * 32 + quad * 8);
    __syncthreads();  // B1: barrier drain (vmcnt 0) completes K DMA

    // S^T = K Q^T: D[m=j][n=i]; lane holds 16 j-values for i = wv*16+l16
    f32x4 s[4];
#pragma unroll
    for (int js = 0; js < 4; ++js) s[js] = (f32x4){0.f, 0.f, 0.f, 0.f};
#pragma unroll
    for (int kc = 0; kc < 8; ++kc) {
#pragma unroll
      for (int js = 0; js < 4; ++js) {
        half8 kf = *(const half8*)&Ks[(js * 16 + l16) * 256 + ((kc * 32 + quad * 8) ^ kswz)];
        s[js] = MFMAH(kf, qf[kc], s[js]);
      }
    }

    // online softmax (exp2 domain), in-lane over 16 j + cross-quad reduce
    float a[16];
    float mx = -1e30f;
#pragma unroll
    for (int js = 0; js < 4; ++js)
#pragma unroll
      for (int r = 0; r < 4; ++r) {
        float v = s[js][r] * mvalL;
        a[js * 4 + r] = v;
        mx = fmaxf(mx, v);
      }
    mx = fmaxf(mx, __shfl_xor(mx, 16));
    mx = fmaxf(mx, __shfl_xor(mx, 32));
    const float mnew = fmaxf(m_run, mx);
    const float alpha = exp2f(m_run - mnew);
    m_run = mnew;
    float psum = 0.f;
#pragma unroll
    for (int js = 0; js < 4; ++js) {
      float p0 = exp2f(a[js * 4 + 0] - mnew);
      float p1 = exp2f(a[js * 4 + 1] - mnew);
      float p2 = exp2f(a[js * 4 + 2] - mnew);
      float p3 = exp2f(a[js * 4 + 3] - mnew);
      psum += (p0 + p1) + (p2 + p3);
      half4 hp = {(_Float16)p0, (_Float16)p1, (_Float16)p2, (_Float16)p3};
      // P[i][j]: i = wv*16+l16, j = js*16 + quad*4 + r
      *(half4*)&Ps[pb][wv * 16 + l16][js * 16 + quad * 4] = hp;
    }
    psum += __shfl_xor(psum, 16);
    psum += __shfl_xor(psum, 32);
    l_run = l_run * alpha + psum;
    if (quad == 0) Al[pb][wv * 16 + l16] = alpha;
    __syncthreads();  // B2: Ps/Al visible; all Ks reads of jt complete

    // issue NEXT K tile's DMA now -> latency hidden under PV + next loop-top
    if (jt < 63) {
      const _Float16* srcn = Kb + (size_t)((jt + 1) * 64 + jrow) * CDIM + scol;
#pragma unroll
      for (int st = 0; st < 8; ++st)
        GLOAD_LDS16(srcn + (size_t)st * 8 * CDIM, ldst0 + st * 4096);
    }

    // O rescale + O += P V  (wave covers all 64 i, channels [wv*64, +64))
    f32x4 av[4];
#pragma unroll
    for (int g = 0; g < 4; ++g) av[g] = *(const f32x4*)&Al[pb][g * 16 + quad * 4];
#pragma unroll
    for (int g = 0; g < 4; ++g)
#pragma unroll
      for (int cg = 0; cg < 4; ++cg)
#pragma unroll
        for (int r = 0; r < 4; ++r) O[g][cg][r] *= av[g][r];
#pragma unroll
    for (int kk = 0; kk < 2; ++kk) {
      half8 pa[4];
#pragma unroll
      for (int g = 0; g < 4; ++g)
        pa[g] = *(const half8*)&Ps[pb][g * 16 + l16][kk * 32 + quad * 8];
#pragma unroll
      for (int g = 0; g < 4; ++g)
#pragma unroll
        for (int cg = 0; cg < 4; ++cg)
          O[g][cg] = MFMAH(pa[g], vf[kk][cg], O[g][cg]);
    }
  }

  // publish 1/l, then blended epilogue
  if (quad == 0) Li[wv * 16 + l16] = 1.0f / l_run;
  __syncthreads();
#pragma unroll
  for (int g = 0; g < 4; ++g) {
    f32x4 li4 = *(const f32x4*)&Li[g * 16 + quad * 4];
    const int i = i0 + g * 16 + quad * 4;
    float4 m4 = *(const float4*)&mask[(size_t)b * NDIM + i];
#pragma unroll
    for (int cg = 0; cg < 4; ++cg) {
      const int c = wv * 64 + cg * 16 + l16;
      const size_t base = ((size_t)(b * CDIM + c)) * NDIM + i;
      float4 q4 = *(const float4*)(queries + base);
      float4 o4;
      o4.x = q4.x * m4.x + (1.f - m4.x) * (O[g][cg][0] * li4[0]);
      o4.y = q4.y * m4.y + (1.f - m4.y) * (O[g][cg][1] * li4[1]);
      o4.z = q4.z * m4.z + (1.f - m4.z) * (O[g][cg][2] * li4[2]);
      o4.w = q4.w * m4.w + (1.f - m4.w) * (O[g][cg][3] * li4[3]);
      *(float4*)(out + base) = o4;
    }
  }
}

extern "C" void kernel_launch(void* const* d_in, const int* in_sizes, int n_in,
                              void* d_out, int out_size, void* d_ws, size_t ws_size,
                              hipStream_t stream) {
  const float* queries = (const float*)d_in[0];
  const float* keys    = (const float*)d_in[1];
  const float* mask    = (const float*)d_in[2];
  const float* Wq = (const float*)d_in[3];
  const float* bq = (const float*)d_in[4];
  const float* Wk = (const float*)d_in[5];
  const float* bk = (const float*)d_in[6];
  const float* Wv = (const float*)d_in[7];
  const float* bv = (const float*)d_in[8];
  float* out = (float*)d_out;

  const size_t elems = (size_t)8 * NDIM * CDIM;
  _Float16* Qh = (_Float16*)d_ws;
  _Float16* Kh = Qh + elems;
  _Float16* Vh = Kh + elems;
  _Float16* Wc = Vh + elems;   // 3*65536 fp16

  cast_w_kernel<<<dim3(192), 256, 0, stream>>>(Wq, Wk, Wv, Wc);
  proj_kernel<<<dim3(32, 1, 24), 256, 0, stream>>>(
      queries, keys, Wc, bq, bk, bv, Qh, Kh, Vh);
  attn_kernel<<<dim3(512), 256, 0, stream>>>(
      queries, mask, Qh, Kh, Vh, out);
}